// Round 14
// baseline (167.007 us; speedup 1.0000x reference)
//
#include <hip/hip_runtime.h>
#include <stdint.h>
#include <stddef.h>

// ---------------- problem constants ----------------
#define NB 4
#define NT 2048
#define NC 1024
#define NH 16
#define ND 64
#define NM (NB*NT)   // 8192 rows

typedef __bf16 bf16_t;
typedef __attribute__((ext_vector_type(8)))  __bf16 bf16x8;
typedef __attribute__((ext_vector_type(4)))  __bf16 bf16x4;
typedef __attribute__((ext_vector_type(2)))  __bf16 bf16x2;
typedef __attribute__((ext_vector_type(4)))  float  f32x4;
typedef __attribute__((ext_vector_type(16))) float  f32x16;
typedef __attribute__((ext_vector_type(4)))  unsigned int u32x4;

// (1/sqrt(64)) * log2(e) — folded into q at the QKV-GEMM epilogue
#define QK_SCALE_LOG2E 0.18033688011112042f

__device__ __forceinline__ f32x4 mfma_bf16(bf16x8 a, bf16x8 b, f32x4 c) {
  return __builtin_amdgcn_mfma_f32_16x16x32_bf16(a, b, c, 0, 0, 0);
}
__device__ __forceinline__ f32x16 mfma32(bf16x8 a, bf16x8 b, f32x16 c) {
  return __builtin_amdgcn_mfma_f32_32x32x16_bf16(a, b, c, 0, 0, 0);
}

// async global->LDS, 16B per lane. LDS dest is wave-uniform base + lane*16.
__device__ __forceinline__ void gld_lds16(const void* g, void* l) {
  __builtin_amdgcn_global_load_lds(
      (const __attribute__((address_space(1))) void*)g,
      (__attribute__((address_space(3))) void*)l, 16, 0, 0);
}

// pack two f32 -> one u32 of 2 bf16 (compiler emits v_cvt_pk_bf16_f32)
__device__ __forceinline__ unsigned int pack_bf16(float a, float b) {
  bf16x2 t; t[0] = (bf16_t)a; t[1] = (bf16_t)b;
  return __builtin_bit_cast(unsigned int, t);
}

// v_permlane32_swap_b32: a' = [a_lo | b_lo], b' = [a_hi | b_hi]
#if __has_builtin(__builtin_amdgcn_permlane32_swap)
typedef __attribute__((ext_vector_type(2))) unsigned int u32x2;
__device__ __forceinline__ void plswap(unsigned int &a, unsigned int &b) {
  u32x2 r = __builtin_amdgcn_permlane32_swap(a, b, false, false);
  a = r[0]; b = r[1];
}
#else
__device__ __forceinline__ void plswap(unsigned int &a, unsigned int &b) {
  asm volatile("s_nop 1\n\tv_permlane32_swap_b32 %0, %1\n\ts_nop 1"
               : "+v"(a), "+v"(b));
}
#endif

// ------- prep: cast x (f32->bf16) AND transpose+cast all four W, ONE launch --
__global__ __launch_bounds__(256) void prep_kernel(
    const float* __restrict__ x, const float* __restrict__ Wq,
    const float* __restrict__ Wk, const float* __restrict__ Wv,
    const float* __restrict__ Wo,
    bf16_t* __restrict__ xb, bf16_t* __restrict__ Tq, bf16_t* __restrict__ Tk,
    bf16_t* __restrict__ Tv, bf16_t* __restrict__ To) {
  __shared__ float tile[32][33];
  if (blockIdx.x < 4096) {
    const int wsel = blockIdx.x >> 10;
    const float* W = (wsel == 0) ? Wq : (wsel == 1) ? Wk : (wsel == 2) ? Wv : Wo;
    bf16_t*     WT = (wsel == 0) ? Tq : (wsel == 1) ? Tk : (wsel == 2) ? Tv : To;
    const int blk = blockIdx.x & 1023;
    const int t = threadIdx.x;
    const int tx = t & 31, ty = t >> 5;        // ty in 0..7
    const int k0 = (blk & 31) << 5;
    const int n0 = (blk >> 5) << 5;
#pragma unroll
    for (int i = 0; i < 4; ++i)
      tile[ty + 8*i][tx] = W[(size_t)(k0 + ty + 8*i)*NC + n0 + tx];
    __syncthreads();
#pragma unroll
    for (int i = 0; i < 4; ++i)
      WT[(size_t)(n0 + ty + 8*i)*NC + k0 + tx] = (bf16_t)tile[tx][ty + 8*i];
  } else {
    const int n4 = NM*NC/4;
    const int stride = 2048 * 256;
    for (int i = (blockIdx.x - 4096) * 256 + threadIdx.x; i < n4; i += stride) {
      float4 v = reinterpret_cast<const float4*>(x)[i];
      bf16x4 o;
      o[0] = (bf16_t)v.x; o[1] = (bf16_t)v.y; o[2] = (bf16_t)v.z; o[3] = (bf16_t)v.w;
      reinterpret_cast<bf16x4*>(xb)[i] = o;
    }
  }
}

// ------- GEMM v3: C = A[MxK] * BT[NxK]^T, 256x128 tile, TRIPLE-buffer -------
// 8 waves (4M x 2N), 512 threads, per-wave C = 64x64 (acc[4][4]). BK=64.
// LDS 144KB: 3 buffers x (A 32KB @0, B 16KB @32768), stride 49152. 1 block/CU
// (was already 1 at 96KB, so the 3rd buffer is free occupancy-wise).
// Pipeline (T4, counted vmcnt): prologue stages k=0,1. Per K-step:
//   wait vmcnt(6)   <- stage(k) landed; stage(k+1)'s 6 loads STAY IN FLIGHT
//   raw s_barrier   <- all waves' stage(k) visible
//   issue stage(k+2) into buffer (k+2)%3 (its readers finished pre-barrier)
//   ds_read + MFMA on buffer k%3
// Loads get TWO compute phases (~1000 cyc) to cover ~900 cyc HBM latency;
// the old 1-deep vmcnt(0) gave only one (~450 cyc) -> per-step stall.
// Last iteration drains vmcnt(0). Bijective XCD swizzle (gridDim%8==0).
// MODE 0: bf16 q (PRE-SCALED by QK_SCALE_LOG2E), k in [B,H,T,D] + bias;
//         V blocks (block-uniform n0>=2048) write V TRANSPOSED [B,H,D,T]
//         via the LDS-transposed epilogue.  MODE 1: fp32 out + bias.
template<int MODE>
__global__ __launch_bounds__(512, 2) void gemm_bt256_kernel(
    const bf16_t* __restrict__ A, const bf16_t* __restrict__ BT,
    int M, int N, int K,
    bf16_t* __restrict__ qo, bf16_t* __restrict__ ko, bf16_t* __restrict__ vo,
    const float* __restrict__ b0, const float* __restrict__ b1, const float* __restrict__ b2,
    float* __restrict__ outp, const float* __restrict__ bo)
{
  const int tid  = threadIdx.x;
  const int lane = tid & 63;
  const int wv   = tid >> 6;                // 0..7
  const int wr   = wv >> 1, wc = wv & 1;    // 4 M-waves x 2 N-waves
  const int l15  = lane & 15, lg = lane >> 4;

  const int nbn = N >> 7;                   // 128-col tiles
  const int cpx = gridDim.x >> 3;           // gridDim % 8 == 0 (bijective)
  const int swz = (blockIdx.x & 7)*cpx + (blockIdx.x >> 3);
  const int bm = swz / nbn, bn = swz % nbn;
  const int m0 = bm << 8, n0 = bn << 7;

  __shared__ char smem[147456];             // 3 x (A 32KB @0, B 16KB @32768)

  f32x4 acc[4][4] = {};

  int offa[4], offb[2];
#pragma unroll
  for (int p = 0; p < 4; ++p) {
    const int c = p*512 + tid;
    const int row = c >> 3, ch = (c & 7) ^ (row & 7);
    offa[p] = row*K + (ch << 3);
  }
#pragma unroll
  for (int p = 0; p < 2; ++p) {
    const int c = p*512 + tid;
    const int row = c >> 3, ch = (c & 7) ^ (row & 7);
    offb[p] = row*K + (ch << 3);
  }
  const int sega = wv << 10;                // wave-uniform 1KB segment

  const bf16_t* Ab = A  + (size_t)m0 * K;
  const bf16_t* Bb = BT + (size_t)n0 * K;

  const int nkt = K >> 6;

  // prologue: stage K-steps 0 and 1 (12 loads in flight)
#pragma unroll
  for (int s = 0; s < 2; ++s) {
    char* const As = smem + s*49152;
    char* const Bs = As + 32768;
    const int k0 = s << 6;
#pragma unroll
    for (int p = 0; p < 4; ++p) gld_lds16(Ab + k0 + offa[p], As + p*8192 + sega);
#pragma unroll
    for (int p = 0; p < 2; ++p) gld_lds16(Bb + k0 + offb[p], Bs + p*8192 + sega);
  }

  for (int kt = 0; kt < nkt; ++kt) {
    char* const As = smem + (kt % 3)*49152;
    char* const Bs = As + 32768;

    // stage(kt) landed; stage(kt+1) (if any) stays in flight across this step
    if (kt < nkt - 1) { asm volatile("s_waitcnt vmcnt(6)" ::: "memory"); }
    else              { asm volatile("s_waitcnt vmcnt(0)" ::: "memory"); }
    __builtin_amdgcn_s_barrier();
    __builtin_amdgcn_sched_barrier(0);

    if (kt + 2 < nkt) {
      char* const An = smem + ((kt + 2) % 3)*49152;
      char* const Bn = An + 32768;
      const int k0 = (kt + 2) << 6;
#pragma unroll
      for (int p = 0; p < 4; ++p) gld_lds16(Ab + k0 + offa[p], An + p*8192 + sega);
#pragma unroll
      for (int p = 0; p < 2; ++p) gld_lds16(Bb + k0 + offb[p], Bn + p*8192 + sega);
      __builtin_amdgcn_sched_barrier(0);    // pin stage-issue early
    }

#pragma unroll
    for (int ks = 0; ks < 2; ++ks) {
      bf16x8 af[4], bfr[4];
#pragma unroll
      for (int fr = 0; fr < 4; ++fr) {
        const int row = wr*64 + fr*16 + l15;          // 0..255
        const int ch  = (ks*4 + lg) ^ (row & 7);
        af[fr] = *reinterpret_cast<const bf16x8*>(As + row*128 + ch*16);
      }
#pragma unroll
      for (int fc = 0; fc < 4; ++fc) {
        const int row = wc*64 + fc*16 + l15;          // 0..127
        const int ch  = (ks*4 + lg) ^ (row & 7);
        bfr[fc] = *reinterpret_cast<const bf16x8*>(Bs + row*128 + ch*16);
      }
      __builtin_amdgcn_s_setprio(1);
#pragma unroll
      for (int fr = 0; fr < 4; ++fr)
#pragma unroll
        for (int fc = 0; fc < 4; ++fc)
          acc[fr][fc] = mfma_bf16(af[fr], bfr[fc], acc[fr][fc]);
      __builtin_amdgcn_s_setprio(0);
    }
  }

  // ---- epilogue. C/D layout: col=lane&15, row=(lane>>4)*4+reg.
  if (MODE == 0 && n0 >= 2*NC) {
    // V block (block-uniform): produce v^T [B,H,D,T] via LDS transpose.
    bf16_t* vbuf = (bf16_t*)smem;           // 128*264*2 = 67584 <= 147456
    const int VSTR = 264;
    __syncthreads();                        // K-loop LDS reads fully done
#pragma unroll
    for (int fr = 0; fr < 4; ++fr) {
#pragma unroll
      for (int fc = 0; fc < 4; ++fc) {
        const int zl = wc*64 + fc*16 + l15;           // 0..127
        const int tl = wr*64 + fr*16 + (lg << 2);     // 0..255, multiple of 4
        const float bias = b2[(n0 - 2*NC) + zl];
        bf16x4 ov;
#pragma unroll
        for (int r = 0; r < 4; ++r) ov[r] = (bf16_t)(acc[fr][fc][r] + bias);
        *reinterpret_cast<bf16x4*>(&vbuf[zl*VSTR + tl]) = ov;
      }
    }
    __syncthreads();
    const int zl  = tid >> 2;
    const int t0l = (tid & 3) << 6;
    const int zg  = (n0 - 2*NC) + zl;       // 0..1023
    const int h   = zg >> 6, d = zg & 63;
    const int bbv = m0 >> 11;               // block spans one b (256 | 2048)
    bf16_t* dst = vo + ((((size_t)bbv*NH + h)*ND + d)*NT) + (m0 & (NT-1)) + t0l;
#pragma unroll
    for (int u = 0; u < 8; ++u)
      *reinterpret_cast<bf16x8*>(dst + u*8) =
          *reinterpret_cast<const bf16x8*>(&vbuf[zl*VSTR + t0l + u*8]);
  } else {
#pragma unroll
    for (int fr = 0; fr < 4; ++fr) {
#pragma unroll
      for (int fc = 0; fc < 4; ++fc) {
        const int mrow0 = m0 + wr*64 + fr*16 + (lg << 2);
        const int ncol  = n0 + wc*64 + fc*16 + l15;
        if (MODE == 0) {
          const int mat = ncol >> 10, c = ncol & 1023;   // mat in {0,1} here
          const int h = c >> 6, d = c & 63;
          bf16_t* dst = (mat == 0) ? qo : ko;
          const float* bptr = (mat == 0) ? b0 : b1;
          const float bias = bptr[c];
          const float scl = (mat == 0) ? QK_SCALE_LOG2E : 1.0f;
#pragma unroll
          for (int r = 0; r < 4; ++r) {
            const int mm = mrow0 + r;
            const int bb = mm >> 11, tt = mm & (NT - 1);
            dst[((((size_t)bb*NH + h)*NT + tt) << 6) + d] =
                (bf16_t)((acc[fr][fc][r] + bias) * scl);
          }
        } else {
          const float bias = bo[ncol];
#pragma unroll
          for (int r = 0; r < 4; ++r)
            outp[(size_t)(mrow0 + r)*N + ncol] = acc[fr][fc][r] + bias;
        }
      }
    }
  }
}

// ---------------- flash attention v9 (causal), balanced causal-pair tiling ---
// (r12's kernel, best measured ~70.1us — r13's dual-tile was serialized by
// the compiler and slightly slower; reverted. Attn frozen at this plateau.)
__global__ __launch_bounds__(256, 2) void attn_kernel(
    const bf16_t* __restrict__ q, const bf16_t* __restrict__ k, const bf16_t* __restrict__ vt,
    bf16_t* __restrict__ o)
{
  const int tid  = threadIdx.x;
  const int lane = tid & 63;
  const int wv   = tid >> 6;                 // 0..3
  const int l31  = lane & 31, h = lane >> 5;

  const int tpair = blockIdx.x >> 6;         // 0..7
  const int bh    = blockIdx.x & 63;
  const int bb = bh >> 4, hh = bh & 15;

  __shared__ char smem[65536];
  char* const ks0 = smem;                    // K: [128 rows][128B], swizzled
  char* const ks1 = smem + 16384;
  char* const vs0 = smem + 32768;            // V^T: [64 rows][256B], swizzled
  char* const vs1 = smem + 49152;

  const size_t base = (size_t)bh * (NT * ND);
  const bf16_t* Kg = k  + base;              // [t][d], row stride 64
  const bf16_t* Vg = vt + base;              // [d][t], row stride 2048

  // staging geometry: 4 K-chunks + 4 V-chunks (16B) per thread per phase.
  int offk[4], offv[4], segb[4];
#pragma unroll
  for (int p = 0; p < 4; ++p) {
    const int c = p*256 + tid;               // 0..1023
    const int krow = c >> 3;
    const int kch  = (c & 7) ^ (krow & 7);
    offk[p] = krow*ND + (kch << 3);
    const int vrow = c >> 4;
    const int vdc  = (c & 15) ^ (vrow & 15);
    offv[p] = vrow*NT + (vdc << 3);
    segb[p] = (p*4 + wv) << 10;
  }

  // ones A-operand for the l-accumulator MFMA
  bf16x8 ones8;
#pragma unroll
  for (int jj2 = 0; jj2 < 8; ++jj2) ones8[jj2] = (bf16_t)1.0f;

  // prologue: stage kv phase 0 (needed by both passes' tiles) into buf0
#pragma unroll
  for (int p = 0; p < 4; ++p) {
    gld_lds16(Kg + offk[p], ks0 + segb[p]);
    gld_lds16(Vg + offv[p], vs0 + segb[p]);
  }

  int jj = 0;                                // global phase counter (parity)

#pragma unroll 1
  for (int pass = 0; pass < 2; ++pass) {
    const int tile = (pass == 0) ? tpair : 15 - tpair;
    const int q0   = tile << 7;              // 128 q rows per tile
    const int q0w  = q0 + wv*32;
    const int qg   = q0w + l31;              // this lane's q row

    // Q as B-operand fragments: lane holds col q=l31, k = 16*ds + 8*h + j
    bf16x8 qf[4];
    {
      const bf16_t* Qg = q + base + (size_t)qg*ND + 8*h;
#pragma unroll
      for (int ds = 0; ds < 4; ++ds)
        qf[ds] = *reinterpret_cast<const bf16x8*>(Qg + 16*ds);
    }

    f32x16 oc[2] = {};                       // O^T accum: q=l31, d=32*da+kc+4h
    f32x16 lacc = {};                        // all 16 regs = running sum_k P

    const int nkv = tile + 1;                // 128-key phases for this tile

#pragma unroll 1
    for (int j = 0; j < nkv; ++j, ++jj) {
      const bool cur1 = (jj & 1) != 0;
      char* const Kc = cur1 ? ks1 : ks0;
      char* const Vc = cur1 ? vs1 : vs0;

      asm volatile("s_waitcnt vmcnt(0)" ::: "memory");
      __builtin_amdgcn_s_barrier();
      __builtin_amdgcn_sched_barrier(0);

      // prefetch: next phase of this tile, or phase 0 of the partner tile
      int nj = (j + 1 < nkv) ? (j + 1) : ((pass == 0) ? 0 : -1);
      if (nj >= 0) {
        char* const Kn = cur1 ? ks0 : ks1;
        char* const Vn = cur1 ? vs0 : vs1;
        const bf16_t* kp = Kg + (size_t)nj*(128*ND);
        const bf16_t* vp = Vg + (size_t)nj*128;
#pragma unroll
        for (int p = 0; p < 4; ++p) {
          gld_lds16(kp + offk[p], Kn + segb[p]);
          gld_lds16(vp + offv[p], Vn + segb[p]);
        }
        __builtin_amdgcn_sched_barrier(0);   // pin stage-issue early
      }

      const int ktile0 = j << 7;
#pragma unroll 1
      for (int hf = 0; hf < 2; ++hf) {
        const int kb0 = ktile0 + (hf << 6);  // first key of this 64-key half
        if (kb0 > q0w + 31) break;           // wave-uniform

        // ---- S^T = mfma32(K, Q): st[kt], q=l31, key = kb0 + 32kt + kc + 4h
        f32x16 st[2] = {};
        __builtin_amdgcn_s_setprio(1);
#pragma unroll
        for (int ds = 0; ds < 4; ++ds) {
#pragma unroll
          for (int kt = 0; kt < 2; ++kt) {
            const int row = (hf*2 + kt)*32 + l31;
            const int cl  = (2*ds + h) ^ (row & 7);
            const bf16x8 kfr = *reinterpret_cast<const bf16x8*>(Kc + row*128 + cl*16);
            st[kt] = mfma32(kfr, qf[ds], st[kt]);
          }
        }
        __builtin_amdgcn_s_setprio(0);

        // ---- P = 2^S (shift-free); mask only when the half crosses the diag
        if (kb0 + 63 > q0w) {
          const int qrel = qg - kb0 - 4*h;   // masked iff 32kt + kc > qrel
#pragma unroll
          for (int kt = 0; kt < 2; ++kt)
#pragma unroll
            for (int r = 0; r < 16; ++r) {
              const int kc = (r & 3) + 8*(r >> 2) + 32*kt;
              st[kt][r] = (kc > qrel) ? 0.0f : exp2f(st[kt][r]);
            }
        } else {
#pragma unroll
          for (int kt = 0; kt < 2; ++kt)
#pragma unroll
            for (int r = 0; r < 16; ++r)
              st[kt][r] = exp2f(st[kt][r]);
        }

        // ---- pack P -> B-frags (2 permlane32_swap per 16-key group);
        //      PV: O^T += mfma32(V^T, P); l += mfma32(ones, P)
#pragma unroll
        for (int kt = 0; kt < 2; ++kt) {
#pragma unroll
          for (int g = 0; g < 2; ++g) {
            unsigned int wa = pack_bf16(st[kt][8*g + 0], st[kt][8*g + 1]);
            unsigned int wb = pack_bf16(st[kt][8*g + 2], st[kt][8*g + 3]);
            unsigned int wc = pack_bf16(st[kt][8*g + 4], st[kt][8*g + 5]);
            unsigned int wd = pack_bf16(st[kt][8*g + 6], st[kt][8*g + 7]);
            plswap(wa, wc);   // wa=word0, wc=word2
            plswap(wb, wd);   // wb=word1, wd=word3
            u32x4 pb; pb[0] = wa; pb[1] = wb; pb[2] = wc; pb[3] = wd;
            const bf16x8 pf = __builtin_bit_cast(bf16x8, pb);
            const int cv = 2*(4*hf + 2*kt + g) + h;  // 16B chunk in 256B V row
            __builtin_amdgcn_s_setprio(1);
            lacc = mfma32(ones8, pf, lacc);
#pragma unroll
            for (int da = 0; da < 2; ++da) {
              const int row = 32*da + l31;
              const int lcv = cv ^ (row & 15);
              const bf16x8 vf = *reinterpret_cast<const bf16x8*>(Vc + row*256 + lcv*16);
              oc[da] = mfma32(vf, pf, oc[da]);
            }
            __builtin_amdgcn_s_setprio(0);
          }
        }
      }
    }

    // ---- normalize + store [b][t][h*64+d] bf16, 8B per (da,u)
    const float rl = 1.0f / lacc[0];
    bf16_t* orow = o + ((size_t)bb*NT + qg)*NC + hh*ND;
#pragma unroll
    for (int da = 0; da < 2; ++da) {
#pragma unroll
      for (int u = 0; u < 4; ++u) {
        bf16x4 ov;
#pragma unroll
        for (int jj3 = 0; jj3 < 4; ++jj3) ov[jj3] = (bf16_t)(oc[da][4*u + jj3] * rl);
        *reinterpret_cast<bf16x4*>(orow + 32*da + 8*u + 4*h) = ov;
      }
    }
  }
}

// ---------------- launcher ----------------
extern "C" void kernel_launch(void* const* d_in, const int* in_sizes, int n_in,
                              void* d_out, int out_size, void* d_ws, size_t ws_size,
                              hipStream_t stream) {
  (void)in_sizes; (void)n_in; (void)out_size;
  const float* x  = (const float*)d_in[0];
  const float* Wq = (const float*)d_in[1];
  const float* bq = (const float*)d_in[2];
  const float* Wk = (const float*)d_in[3];
  const float* bk = (const float*)d_in[4];
  const float* Wv = (const float*)d_in[5];
  const float* bv = (const float*)d_in[6];
  const float* Wo = (const float*)d_in[7];
  const float* bo = (const float*)d_in[8];
  float* out = (float*)d_out;

  // workspace layout (bytes)
  const size_t off_xb    = 0;                         // 16 MB
  const size_t off_wqkvT = 16777216;                  // 6 MB
  const size_t off_woT   = 23068672;                  // 2 MB
  const size_t off_q     = 25165824;                  // 16 MB
  const size_t off_k     = 41943040;                  // 16 MB
  const size_t off_v     = 58720256;                  // 16 MB (V^T: [B,H,D,T])
  const size_t off_attn  = 75497472;                  // 16 MB
  const size_t need      = 92274688;
  if (ws_size < need) return;

  char* ws = (char*)d_ws;
  bf16_t* xb    = (bf16_t*)(ws + off_xb);
  bf16_t* wqkvT = (bf16_t*)(ws + off_wqkvT);
  bf16_t* woT   = (bf16_t*)(ws + off_woT);
  bf16_t* qb    = (bf16_t*)(ws + off_q);
  bf16_t* kb    = (bf16_t*)(ws + off_k);
  bf16_t* vtb   = (bf16_t*)(ws + off_v);              // v^T, written by GEMM
  bf16_t* attnb = (bf16_t*)(ws + off_attn);

  prep_kernel<<<dim3(6144), dim3(256), 0, stream>>>(
      x, Wq, Wk, Wv, Wo, xb, wqkvT, wqkvT + 1048576, wqkvT + 2097152, woT);

  // QKV: M=8192, N=3072 -> (8192/256)*(3072/128) = 32*24 = 768 blocks (3/CU)
  gemm_bt256_kernel<0><<<dim3(768), dim3(512), 0, stream>>>(
      xb, wqkvT, NM, 3*NC, NC, qb, kb, vtb, bq, bk, bv, nullptr, nullptr);

  attn_kernel<<<dim3(8*64), dim3(256), 0, stream>>>(qb, kb, vtb, attnb);

  // out-proj: M=8192, N=1024 -> 32*8 = 256 blocks (1/CU)
  gemm_bt256_kernel<1><<<dim3(256), dim3(512), 0, stream>>>(
      attnb, woT, NM, NC, NC, nullptr, nullptr, nullptr, nullptr, nullptr, nullptr,
      out, bo);
}

// Round 15
// 160.760 us; speedup vs baseline: 1.0389x; 1.0389x over previous
//
#include <hip/hip_runtime.h>
#include <stdint.h>
#include <stddef.h>

// ---------------- problem constants ----------------
#define NB 4
#define NT 2048
#define NC 1024
#define NH 16
#define ND 64
#define NM (NB*NT)   // 8192 rows

typedef __bf16 bf16_t;
typedef __attribute__((ext_vector_type(8)))  __bf16 bf16x8;
typedef __attribute__((ext_vector_type(4)))  __bf16 bf16x4;
typedef __attribute__((ext_vector_type(2)))  __bf16 bf16x2;
typedef __attribute__((ext_vector_type(4)))  float  f32x4;
typedef __attribute__((ext_vector_type(16))) float  f32x16;
typedef __attribute__((ext_vector_type(4)))  unsigned int u32x4;

// (1/sqrt(64)) * log2(e) — folded into q at the QKV-GEMM epilogue
#define QK_SCALE_LOG2E 0.18033688011112042f

__device__ __forceinline__ f32x4 mfma_bf16(bf16x8 a, bf16x8 b, f32x4 c) {
  return __builtin_amdgcn_mfma_f32_16x16x32_bf16(a, b, c, 0, 0, 0);
}
__device__ __forceinline__ f32x16 mfma32(bf16x8 a, bf16x8 b, f32x16 c) {
  return __builtin_amdgcn_mfma_f32_32x32x16_bf16(a, b, c, 0, 0, 0);
}

// async global->LDS, 16B per lane. LDS dest is wave-uniform base + lane*16.
__device__ __forceinline__ void gld_lds16(const void* g, void* l) {
  __builtin_amdgcn_global_load_lds(
      (const __attribute__((address_space(1))) void*)g,
      (__attribute__((address_space(3))) void*)l, 16, 0, 0);
}

// pack two f32 -> one u32 of 2 bf16 (compiler emits v_cvt_pk_bf16_f32)
__device__ __forceinline__ unsigned int pack_bf16(float a, float b) {
  bf16x2 t; t[0] = (bf16_t)a; t[1] = (bf16_t)b;
  return __builtin_bit_cast(unsigned int, t);
}

// v_permlane32_swap_b32: a' = [a_lo | b_lo], b' = [a_hi | b_hi]
#if __has_builtin(__builtin_amdgcn_permlane32_swap)
typedef __attribute__((ext_vector_type(2))) unsigned int u32x2;
__device__ __forceinline__ void plswap(unsigned int &a, unsigned int &b) {
  u32x2 r = __builtin_amdgcn_permlane32_swap(a, b, false, false);
  a = r[0]; b = r[1];
}
#else
__device__ __forceinline__ void plswap(unsigned int &a, unsigned int &b) {
  asm volatile("s_nop 1\n\tv_permlane32_swap_b32 %0, %1\n\ts_nop 1"
               : "+v"(a), "+v"(b));
}
#endif

// ------- prep: cast x (f32->bf16) AND transpose+cast all four W, ONE launch --
__global__ __launch_bounds__(256) void prep_kernel(
    const float* __restrict__ x, const float* __restrict__ Wq,
    const float* __restrict__ Wk, const float* __restrict__ Wv,
    const float* __restrict__ Wo,
    bf16_t* __restrict__ xb, bf16_t* __restrict__ Tq, bf16_t* __restrict__ Tk,
    bf16_t* __restrict__ Tv, bf16_t* __restrict__ To) {
  __shared__ float tile[32][33];
  if (blockIdx.x < 4096) {
    const int wsel = blockIdx.x >> 10;
    const float* W = (wsel == 0) ? Wq : (wsel == 1) ? Wk : (wsel == 2) ? Wv : Wo;
    bf16_t*     WT = (wsel == 0) ? Tq : (wsel == 1) ? Tk : (wsel == 2) ? Tv : To;
    const int blk = blockIdx.x & 1023;
    const int t = threadIdx.x;
    const int tx = t & 31, ty = t >> 5;        // ty in 0..7
    const int k0 = (blk & 31) << 5;
    const int n0 = (blk >> 5) << 5;
#pragma unroll
    for (int i = 0; i < 4; ++i)
      tile[ty + 8*i][tx] = W[(size_t)(k0 + ty + 8*i)*NC + n0 + tx];
    __syncthreads();
#pragma unroll
    for (int i = 0; i < 4; ++i)
      WT[(size_t)(n0 + ty + 8*i)*NC + k0 + tx] = (bf16_t)tile[tx][ty + 8*i];
  } else {
    const int n4 = NM*NC/4;
    const int stride = 2048 * 256;
    for (int i = (blockIdx.x - 4096) * 256 + threadIdx.x; i < n4; i += stride) {
      float4 v = reinterpret_cast<const float4*>(x)[i];
      bf16x4 o;
      o[0] = (bf16_t)v.x; o[1] = (bf16_t)v.y; o[2] = (bf16_t)v.z; o[3] = (bf16_t)v.w;
      reinterpret_cast<bf16x4*>(xb)[i] = o;
    }
  }
}

// ------- GEMM v2: C = A[MxK] * BT[NxK]^T, 256x128 tile, raw-barrier overlap --
// (r12 version, 2-buffer — r14's triple-buffer regressed and was reverted.)
template<int MODE>
__global__ __launch_bounds__(512, 2) void gemm_bt256_kernel(
    const bf16_t* __restrict__ A, const bf16_t* __restrict__ BT,
    int M, int N, int K,
    bf16_t* __restrict__ qo, bf16_t* __restrict__ ko, bf16_t* __restrict__ vo,
    const float* __restrict__ b0, const float* __restrict__ b1, const float* __restrict__ b2,
    float* __restrict__ outp, const float* __restrict__ bo)
{
  const int tid  = threadIdx.x;
  const int lane = tid & 63;
  const int wv   = tid >> 6;                // 0..7
  const int wr   = wv >> 1, wc = wv & 1;    // 4 M-waves x 2 N-waves
  const int l15  = lane & 15, lg = lane >> 4;

  const int nbn = N >> 7;                   // 128-col tiles
  const int cpx = gridDim.x >> 3;           // gridDim % 8 == 0 (bijective)
  const int swz = (blockIdx.x & 7)*cpx + (blockIdx.x >> 3);
  const int bm = swz / nbn, bn = swz % nbn;
  const int m0 = bm << 8, n0 = bn << 7;

  __shared__ char smem[98304];              // 2 x (A 32KB @0, B 16KB @32768)

  f32x4 acc[4][4] = {};

  int offa[4], offb[2];
#pragma unroll
  for (int p = 0; p < 4; ++p) {
    const int c = p*512 + tid;
    const int row = c >> 3, ch = (c & 7) ^ (row & 7);
    offa[p] = row*K + (ch << 3);
  }
#pragma unroll
  for (int p = 0; p < 2; ++p) {
    const int c = p*512 + tid;
    const int row = c >> 3, ch = (c & 7) ^ (row & 7);
    offb[p] = row*K + (ch << 3);
  }
  const int sega = wv << 10;                // wave-uniform 1KB segment

  const bf16_t* Ab = A  + (size_t)m0 * K;
  const bf16_t* Bb = BT + (size_t)n0 * K;

  const int nkt = K >> 6;

  {
    char* const As = smem;
    char* const Bs = smem + 32768;
#pragma unroll
    for (int p = 0; p < 4; ++p) gld_lds16(Ab + offa[p], As + p*8192 + sega);
#pragma unroll
    for (int p = 0; p < 2; ++p) gld_lds16(Bb + offb[p], Bs + p*8192 + sega);
  }

  for (int kt = 0; kt < nkt; ++kt) {
    char* const As = smem + (kt & 1)*49152;
    char* const Bs = As + 32768;

    asm volatile("s_waitcnt vmcnt(0)" ::: "memory");
    __builtin_amdgcn_s_barrier();
    __builtin_amdgcn_sched_barrier(0);

    if (kt + 1 < nkt) {
      char* const An = smem + ((kt + 1) & 1)*49152;
      char* const Bn = An + 32768;
      const int k0 = (kt + 1) << 6;
#pragma unroll
      for (int p = 0; p < 4; ++p) gld_lds16(Ab + k0 + offa[p], An + p*8192 + sega);
#pragma unroll
      for (int p = 0; p < 2; ++p) gld_lds16(Bb + k0 + offb[p], Bn + p*8192 + sega);
      __builtin_amdgcn_sched_barrier(0);    // pin stage-issue early
    }

#pragma unroll
    for (int ks = 0; ks < 2; ++ks) {
      bf16x8 af[4], bfr[4];
#pragma unroll
      for (int fr = 0; fr < 4; ++fr) {
        const int row = wr*64 + fr*16 + l15;          // 0..255
        const int ch  = (ks*4 + lg) ^ (row & 7);
        af[fr] = *reinterpret_cast<const bf16x8*>(As + row*128 + ch*16);
      }
#pragma unroll
      for (int fc = 0; fc < 4; ++fc) {
        const int row = wc*64 + fc*16 + l15;          // 0..127
        const int ch  = (ks*4 + lg) ^ (row & 7);
        bfr[fc] = *reinterpret_cast<const bf16x8*>(Bs + row*128 + ch*16);
      }
      __builtin_amdgcn_s_setprio(1);
#pragma unroll
      for (int fr = 0; fr < 4; ++fr)
#pragma unroll
        for (int fc = 0; fc < 4; ++fc)
          acc[fr][fc] = mfma_bf16(af[fr], bfr[fc], acc[fr][fc]);
      __builtin_amdgcn_s_setprio(0);
    }
  }

  // ---- epilogue. C/D layout: col=lane&15, row=(lane>>4)*4+reg.
  if (MODE == 0 && n0 >= 2*NC) {
    // V block (block-uniform): produce v^T [B,H,D,T] via LDS transpose.
    bf16_t* vbuf = (bf16_t*)smem;           // 128*264*2 = 67584 <= 98304
    const int VSTR = 264;
    __syncthreads();                        // K-loop LDS reads fully done
#pragma unroll
    for (int fr = 0; fr < 4; ++fr) {
#pragma unroll
      for (int fc = 0; fc < 4; ++fc) {
        const int zl = wc*64 + fc*16 + l15;           // 0..127
        const int tl = wr*64 + fr*16 + (lg << 2);     // 0..255, multiple of 4
        const float bias = b2[(n0 - 2*NC) + zl];
        bf16x4 ov;
#pragma unroll
        for (int r = 0; r < 4; ++r) ov[r] = (bf16_t)(acc[fr][fc][r] + bias);
        *reinterpret_cast<bf16x4*>(&vbuf[zl*VSTR + tl]) = ov;
      }
    }
    __syncthreads();
    const int zl  = tid >> 2;
    const int t0l = (tid & 3) << 6;
    const int zg  = (n0 - 2*NC) + zl;       // 0..1023
    const int h   = zg >> 6, d = zg & 63;
    const int bbv = m0 >> 11;               // block spans one b (256 | 2048)
    bf16_t* dst = vo + ((((size_t)bbv*NH + h)*ND + d)*NT) + (m0 & (NT-1)) + t0l;
#pragma unroll
    for (int u = 0; u < 8; ++u)
      *reinterpret_cast<bf16x8*>(dst + u*8) =
          *reinterpret_cast<const bf16x8*>(&vbuf[zl*VSTR + t0l + u*8]);
  } else {
#pragma unroll
    for (int fr = 0; fr < 4; ++fr) {
#pragma unroll
      for (int fc = 0; fc < 4; ++fc) {
        const int mrow0 = m0 + wr*64 + fr*16 + (lg << 2);
        const int ncol  = n0 + wc*64 + fc*16 + l15;
        if (MODE == 0) {
          const int mat = ncol >> 10, c = ncol & 1023;   // mat in {0,1} here
          const int h = c >> 6, d = c & 63;
          bf16_t* dst = (mat == 0) ? qo : ko;
          const float* bptr = (mat == 0) ? b0 : b1;
          const float bias = bptr[c];
          const float scl = (mat == 0) ? QK_SCALE_LOG2E : 1.0f;
#pragma unroll
          for (int r = 0; r < 4; ++r) {
            const int mm = mrow0 + r;
            const int bb = mm >> 11, tt = mm & (NT - 1);
            dst[((((size_t)bb*NH + h)*NT + tt) << 6) + d] =
                (bf16_t)((acc[fr][fc][r] + bias) * scl);
          }
        } else {
          const float bias = bo[ncol];
#pragma unroll
          for (int r = 0; r < 4; ++r)
            outp[(size_t)(mrow0 + r)*N + ncol] = acc[fr][fc][r] + bias;
        }
      }
    }
  }
}

// ---- flash attention v12 (causal): r9 pair tiling + INTERLEAVED 64-key halves
// r9 structure (17 phases/block, perfectly balanced) unchanged. NEW: the two
// independent 64-key halves of each 128-key phase — previously run serially
// under `#pragma unroll 1` — are interleaved with FORCED simultaneous
// liveness: separate st0/st1 accumulators and sched_barrier(0) pins between
// the QK / exp / PV sections, so the scheduler cannot re-serialize them
// (r13's lambda version let the compiler reuse st[] and serialize; VGPR=116
// proved it). Dual-chain ILP fills the dependency stalls that dominate the
// measured ~9.9K cyc/phase (vs ~3.4K of issue work). ~170 VGPR, no spill at
// the (256,2) cap. Inner math byte-identical to v4-v9.
__global__ __launch_bounds__(256, 2) void attn_kernel(
    const bf16_t* __restrict__ q, const bf16_t* __restrict__ k, const bf16_t* __restrict__ vt,
    bf16_t* __restrict__ o)
{
  const int tid  = threadIdx.x;
  const int lane = tid & 63;
  const int wv   = tid >> 6;                 // 0..3
  const int l31  = lane & 31, h = lane >> 5;

  const int tpair = blockIdx.x >> 6;         // 0..7
  const int bh    = blockIdx.x & 63;
  const int bb = bh >> 4, hh = bh & 15;

  __shared__ char smem[65536];
  char* const ks0 = smem;                    // K: [128 rows][128B], swizzled
  char* const ks1 = smem + 16384;
  char* const vs0 = smem + 32768;            // V^T: [64 rows][256B], swizzled
  char* const vs1 = smem + 49152;

  const size_t base = (size_t)bh * (NT * ND);
  const bf16_t* Kg = k  + base;              // [t][d], row stride 64
  const bf16_t* Vg = vt + base;              // [d][t], row stride 2048

  // staging geometry: 4 K-chunks + 4 V-chunks (16B) per thread per phase.
  int offk[4], offv[4], segb[4];
#pragma unroll
  for (int p = 0; p < 4; ++p) {
    const int c = p*256 + tid;               // 0..1023
    const int krow = c >> 3;
    const int kch  = (c & 7) ^ (krow & 7);
    offk[p] = krow*ND + (kch << 3);
    const int vrow = c >> 4;
    const int vdc  = (c & 15) ^ (vrow & 15);
    offv[p] = vrow*NT + (vdc << 3);
    segb[p] = (p*4 + wv) << 10;
  }

  // ones A-operand for the l-accumulator MFMA
  bf16x8 ones8;
#pragma unroll
  for (int i = 0; i < 8; ++i) ones8[i] = (bf16_t)1.0f;

  // prologue: stage kv phase 0 (needed by both passes' tiles) into buf0
#pragma unroll
  for (int p = 0; p < 4; ++p) {
    gld_lds16(Kg + offk[p], ks0 + segb[p]);
    gld_lds16(Vg + offv[p], vs0 + segb[p]);
  }

  int jj = 0;                                // global phase counter (parity)

#pragma unroll 1
  for (int pass = 0; pass < 2; ++pass) {
    const int tile = (pass == 0) ? tpair : 15 - tpair;
    const int q0   = tile << 7;              // 128 q rows per tile
    const int q0w  = q0 + wv*32;
    const int qg   = q0w + l31;              // this lane's q row

    // Q as B-operand fragments: lane holds col q=l31, k = 16*ds + 8*h + j
    bf16x8 qf[4];
    {
      const bf16_t* Qg = q + base + (size_t)qg*ND + 8*h;
#pragma unroll
      for (int ds = 0; ds < 4; ++ds)
        qf[ds] = *reinterpret_cast<const bf16x8*>(Qg + 16*ds);
    }

    f32x16 oc[2] = {};                       // O^T accum: q=l31, d=32*da+kc+4h
    f32x16 lacc = {};                        // all 16 regs = running sum_k P

    const int nkv = tile + 1;                // 128-key phases for this tile

#pragma unroll 1
    for (int j = 0; j < nkv; ++j, ++jj) {
      const bool cur1 = (jj & 1) != 0;
      char* const Kc = cur1 ? ks1 : ks0;
      char* const Vc = cur1 ? vs1 : vs0;

      asm volatile("s_waitcnt vmcnt(0)" ::: "memory");
      __builtin_amdgcn_s_barrier();
      __builtin_amdgcn_sched_barrier(0);

      // prefetch: next phase of this tile, or phase 0 of the partner tile
      int nj = (j + 1 < nkv) ? (j + 1) : ((pass == 0) ? 0 : -1);
      if (nj >= 0) {
        char* const Kn = cur1 ? ks0 : ks1;
        char* const Vn = cur1 ? vs0 : vs1;
        const bf16_t* kp = Kg + (size_t)nj*(128*ND);
        const bf16_t* vp = Vg + (size_t)nj*128;
#pragma unroll
        for (int p = 0; p < 4; ++p) {
          gld_lds16(kp + offk[p], Kn + segb[p]);
          gld_lds16(vp + offv[p], Vn + segb[p]);
        }
        __builtin_amdgcn_sched_barrier(0);   // pin stage-issue early
      }

      const int ktile0 = j << 7;
      const int kb1 = ktile0 + 64;
      const bool h1 = (kb1 <= q0w + 31);     // wave-uniform: second half live?

      if (h1) {
        // ================= DUAL-HALF INTERLEAVED PATH =================
        f32x16 st0[2] = {}, st1[2] = {};

        // ---- QK both halves (16 MFMA, independent streams)
        __builtin_amdgcn_s_setprio(1);
#pragma unroll
        for (int ds = 0; ds < 4; ++ds) {
#pragma unroll
          for (int kt = 0; kt < 2; ++kt) {
            const int r0 = kt*32 + l31;              // rows 0..63
            const int c0 = (2*ds + h) ^ (r0 & 7);
            const bf16x8 k0 = *reinterpret_cast<const bf16x8*>(Kc + r0*128 + c0*16);
            st0[kt] = mfma32(k0, qf[ds], st0[kt]);
            const int r1 = (2 + kt)*32 + l31;        // rows 64..127
            const int c1 = (2*ds + h) ^ (r1 & 7);
            const bf16x8 k1 = *reinterpret_cast<const bf16x8*>(Kc + r1*128 + c1*16);
            st1[kt] = mfma32(k1, qf[ds], st1[kt]);
          }
        }
        __builtin_amdgcn_s_setprio(0);
        __builtin_amdgcn_sched_barrier(0);   // pin: both st live past here

        // ---- exp both halves (mask only where the half crosses the diag)
        if (ktile0 + 63 > q0w) {
          const int qrel = qg - ktile0 - 4*h;
#pragma unroll
          for (int kt = 0; kt < 2; ++kt)
#pragma unroll
            for (int r = 0; r < 16; ++r) {
              const int kc = (r & 3) + 8*(r >> 2) + 32*kt;
              st0[kt][r] = (kc > qrel) ? 0.0f : exp2f(st0[kt][r]);
            }
        } else {
#pragma unroll
          for (int kt = 0; kt < 2; ++kt)
#pragma unroll
            for (int r = 0; r < 16; ++r)
              st0[kt][r] = exp2f(st0[kt][r]);
        }
        if (kb1 + 63 > q0w) {
          const int qrel = qg - kb1 - 4*h;
#pragma unroll
          for (int kt = 0; kt < 2; ++kt)
#pragma unroll
            for (int r = 0; r < 16; ++r) {
              const int kc = (r & 3) + 8*(r >> 2) + 32*kt;
              st1[kt][r] = (kc > qrel) ? 0.0f : exp2f(st1[kt][r]);
            }
        } else {
#pragma unroll
          for (int kt = 0; kt < 2; ++kt)
#pragma unroll
            for (int r = 0; r < 16; ++r)
              st1[kt][r] = exp2f(st1[kt][r]);
        }
        __builtin_amdgcn_sched_barrier(0);

        // ---- pack + PV, halves interleaved per (kt,g)
#pragma unroll
        for (int kt = 0; kt < 2; ++kt) {
#pragma unroll
          for (int g = 0; g < 2; ++g) {
            // half 0
            {
              unsigned int wa = pack_bf16(st0[kt][8*g + 0], st0[kt][8*g + 1]);
              unsigned int wb = pack_bf16(st0[kt][8*g + 2], st0[kt][8*g + 3]);
              unsigned int wc = pack_bf16(st0[kt][8*g + 4], st0[kt][8*g + 5]);
              unsigned int wd = pack_bf16(st0[kt][8*g + 6], st0[kt][8*g + 7]);
              plswap(wa, wc); plswap(wb, wd);
              u32x4 pb; pb[0] = wa; pb[1] = wb; pb[2] = wc; pb[3] = wd;
              const bf16x8 pf = __builtin_bit_cast(bf16x8, pb);
              const int cv = 2*(2*kt + g) + h;
              __builtin_amdgcn_s_setprio(1);
              lacc = mfma32(ones8, pf, lacc);
#pragma unroll
              for (int da = 0; da < 2; ++da) {
                const int row = 32*da + l31;
                const int lcv = cv ^ (row & 15);
                const bf16x8 vf = *reinterpret_cast<const bf16x8*>(Vc + row*256 + lcv*16);
                oc[da] = mfma32(vf, pf, oc[da]);
              }
              __builtin_amdgcn_s_setprio(0);
            }
            // half 1 (independent of half 0's MFMAs — overlaps them)
            {
              unsigned int wa = pack_bf16(st1[kt][8*g + 0], st1[kt][8*g + 1]);
              unsigned int wb = pack_bf16(st1[kt][8*g + 2], st1[kt][8*g + 3]);
              unsigned int wc = pack_bf16(st1[kt][8*g + 4], st1[kt][8*g + 5]);
              unsigned int wd = pack_bf16(st1[kt][8*g + 6], st1[kt][8*g + 7]);
              plswap(wa, wc); plswap(wb, wd);
              u32x4 pb; pb[0] = wa; pb[1] = wb; pb[2] = wc; pb[3] = wd;
              const bf16x8 pf = __builtin_bit_cast(bf16x8, pb);
              const int cv = 2*(4 + 2*kt + g) + h;
              __builtin_amdgcn_s_setprio(1);
              lacc = mfma32(ones8, pf, lacc);
#pragma unroll
              for (int da = 0; da < 2; ++da) {
                const int row = 32*da + l31;
                const int lcv = cv ^ (row & 15);
                const bf16x8 vf = *reinterpret_cast<const bf16x8*>(Vc + row*256 + lcv*16);
                oc[da] = mfma32(vf, pf, oc[da]);
              }
              __builtin_amdgcn_s_setprio(0);
            }
          }
        }
      } else {
        // ================= SINGLE-HALF PATH (hf=0 only; diag, wv 0/1) ======
        f32x16 st[2] = {};
        __builtin_amdgcn_s_setprio(1);
#pragma unroll
        for (int ds = 0; ds < 4; ++ds) {
#pragma unroll
          for (int kt = 0; kt < 2; ++kt) {
            const int row = kt*32 + l31;
            const int cl  = (2*ds + h) ^ (row & 7);
            const bf16x8 kfr = *reinterpret_cast<const bf16x8*>(Kc + row*128 + cl*16);
            st[kt] = mfma32(kfr, qf[ds], st[kt]);
          }
        }
        __builtin_amdgcn_s_setprio(0);

        if (ktile0 + 63 > q0w) {
          const int qrel = qg - ktile0 - 4*h;
#pragma unroll
          for (int kt = 0; kt < 2; ++kt)
#pragma unroll
            for (int r = 0; r < 16; ++r) {
              const int kc = (r & 3) + 8*(r >> 2) + 32*kt;
              st[kt][r] = (kc > qrel) ? 0.0f : exp2f(st[kt][r]);
            }
        } else {
#pragma unroll
          for (int kt = 0; kt < 2; ++kt)
#pragma unroll
            for (int r = 0; r < 16; ++r)
              st[kt][r] = exp2f(st[kt][r]);
        }

#pragma unroll
        for (int kt = 0; kt < 2; ++kt) {
#pragma unroll
          for (int g = 0; g < 2; ++g) {
            unsigned int wa = pack_bf16(st[kt][8*g + 0], st[kt][8*g + 1]);
            unsigned int wb = pack_bf16(st[kt][8*g + 2], st[kt][8*g + 3]);
            unsigned int wc = pack_bf16(st[kt][8*g + 4], st[kt][8*g + 5]);
            unsigned int wd = pack_bf16(st[kt][8*g + 6], st[kt][8*g + 7]);
            plswap(wa, wc); plswap(wb, wd);
            u32x4 pb; pb[0] = wa; pb[1] = wb; pb[2] = wc; pb[3] = wd;
            const bf16x8 pf = __builtin_bit_cast(bf16x8, pb);
            const int cv = 2*(2*kt + g) + h;
            __builtin_amdgcn_s_setprio(1);
            lacc = mfma32(ones8, pf, lacc);
#pragma unroll
            for (int da = 0; da < 2; ++da) {
              const int row = 32*da + l31;
              const int lcv = cv ^ (row & 15);
              const bf16x8 vf = *reinterpret_cast<const bf16x8*>(Vc + row*256 + lcv*16);
              oc[da] = mfma32(vf, pf, oc[da]);
            }
            __builtin_amdgcn_s_setprio(0);
          }
        }
      }
    }

    // ---- normalize + store [b][t][h*64+d] bf16, 8B per (da,u)
    const float rl = 1.0f / lacc[0];
    bf16_t* orow = o + ((size_t)bb*NT + qg)*NC + hh*ND;
#pragma unroll
    for (int da = 0; da < 2; ++da) {
#pragma unroll
      for (int u = 0; u < 4; ++u) {
        bf16x4 ov;
#pragma unroll
        for (int i = 0; i < 4; ++i) ov[i] = (bf16_t)(oc[da][4*u + i] * rl);
        *reinterpret_cast<bf16x4*>(orow + 32*da + 8*u + 4*h) = ov;
      }
    }
  }
}

// ---------------- launcher ----------------
extern "C" void kernel_launch(void* const* d_in, const int* in_sizes, int n_in,
                              void* d_out, int out_size, void* d_ws, size_t ws_size,
                              hipStream_t stream) {
  (void)in_sizes; (void)n_in; (void)out_size;
  const float* x  = (const float*)d_in[0];
  const float* Wq = (const float*)d_in[1];
  const float* bq = (const float*)d_in[2];
  const float* Wk = (const float*)d_in[3];
  const float* bk = (const float*)d_in[4];
  const float* Wv = (const float*)d_in[5];
  const float* bv = (const float*)d_in[6];
  const float* Wo = (const float*)d_in[7];
  const float* bo = (const float*)d_in[8];
  float* out = (float*)d_out;

  // workspace layout (bytes)
  const size_t off_xb    = 0;                         // 16 MB
  const size_t off_wqkvT = 16777216;                  // 6 MB
  const size_t off_woT   = 23068672;                  // 2 MB
  const size_t off_q     = 25165824;                  // 16 MB
  const size_t off_k     = 41943040;                  // 16 MB
  const size_t off_v     = 58720256;                  // 16 MB (V^T: [B,H,D,T])
  const size_t off_attn  = 75497472;                  // 16 MB
  const size_t need      = 92274688;
  if (ws_size < need) return;

  char* ws = (char*)d_ws;
  bf16_t* xb    = (bf16_t*)(ws + off_xb);
  bf16_t* wqkvT = (bf16_t*)(ws + off_wqkvT);
  bf16_t* woT   = (bf16_t*)(ws + off_woT);
  bf16_t* qb    = (bf16_t*)(ws + off_q);
  bf16_t* kb    = (bf16_t*)(ws + off_k);
  bf16_t* vtb   = (bf16_t*)(ws + off_v);              // v^T, written by GEMM
  bf16_t* attnb = (bf16_t*)(ws + off_attn);

  prep_kernel<<<dim3(6144), dim3(256), 0, stream>>>(
      x, Wq, Wk, Wv, Wo, xb, wqkvT, wqkvT + 1048576, wqkvT + 2097152, woT);

  // QKV: M=8192, N=3072 -> (8192/256)*(3072/128) = 32*24 = 768 blocks (3/CU)
  gemm_bt256_kernel<0><<<dim3(768), dim3(512), 0, stream>>>(
      xb, wqkvT, NM, 3*NC, NC, qb, kb, vtb, bq, bk, bv, nullptr, nullptr);

  attn_kernel<<<dim3(8*64), dim3(256), 0, stream>>>(qb, kb, vtb, attnb);

  // out-proj: M=8192, N=1024 -> 32*8 = 256 blocks (1/CU)
  gemm_bt256_kernel<1><<<dim3(256), dim3(512), 0, stream>>>(
      attnb, woT, NM, NC, NC, nullptr, nullptr, nullptr, nullptr, nullptr, nullptr,
      out, bo);
}